// Round 5
// baseline (114.574 us; speedup 1.0000x reference)
//
#include <hip/hip_runtime.h>
#include <hip/hip_bf16.h>
#include <math.h>

// Chamfer distance via K-packed MFMA, B=8, N=M=8192, D=3, fp32.
//   C[m][n] = q_m.r_n - 0.5*||r_n||^2 via ONE v_mfma_f32_32x32x16_bf16:
//     lanes<32  (k0-7) : A={qh,1, ql,0}  B={rh,wh, rh,wh}
//     lanes>=32 (k8-15): A={qh,1, 0,0}   B={rl,wl, 0,0}
//   (hi/lo bf16 split; dropped ql.rl term ~2^-17 relative)
//   min_j d2 = ||q||^2_fp32 - 2*max_n C, clamped at 0.
// R5: NCHUNK=4 ref-split + 4-wave blocks for occupancy (atomicMax-merged
// partial maxes on order-preserving uint keys); 16B/point records with 8B
// per-lane loads (lane-half selects hi or lo) expanded by 2 v_cndmask.

#define BLOCK 256
#define WAVES 4
#define QPW 64        // queries per wave (two 32-row MFMA groups)
#define NCHUNK 4      // ref-dim split across blockIdx.y

typedef short short8 __attribute__((ext_vector_type(8)));
typedef float f32x16 __attribute__((ext_vector_type(16)));

union U16S { uint4 v; short8 s; };

__device__ __forceinline__ unsigned int bf16hi(float f) {
    __hip_bfloat16 h = __float2bfloat16(f);
    return (unsigned int)*reinterpret_cast<unsigned short*>(&h);
}
__device__ __forceinline__ float bf16f(unsigned int u) {
    unsigned short us = (unsigned short)u;
    __hip_bfloat16 h;
    *reinterpret_cast<unsigned short*>(&h) = us;
    return __bfloat162float(h);
}
__device__ __forceinline__ unsigned int encodeKey(float f) {
    unsigned int u = __float_as_uint(f);
    return (u & 0x80000000u) ? ~u : (u | 0x80000000u);
}
__device__ __forceinline__ float decodeKey(unsigned int u) {
    u = (u & 0x80000000u) ? (u & 0x7FFFFFFFu) : ~u;
    return __uint_as_float(u);
}

__device__ __forceinline__ f32x16 mfma_bf16(short8 a, short8 b, f32x16 c) {
    f32x16 d;
    asm volatile("v_mfma_f32_32x32x16_bf16 %0, %1, %2, %3"
                 : "=v"(d) : "v"(a), "v"(b), "v"(c));
    return d;
}
// >=16 wait cycles between MFMA issue and VALU reads of dests (inline asm
// bypasses the compiler hazard recognizer); data-tied so folds can't hoist.
__device__ __forceinline__ void mfma_fence4(f32x16& a, f32x16& b, f32x16& c, f32x16& d) {
    asm volatile("s_nop 7\n\ts_nop 7" : "+v"(a), "+v"(b), "+v"(c), "+v"(d));
}

// Per point one 16B record: {xh|yh, zh|wh, xl|yl, zl|wl}, w = -0.5*||p||^2.
// Also: keys init to 0 (== below encode of any finite float), out zeroed.
__global__ void prep_kernel(const float* __restrict__ gts, const float* __restrict__ preds,
                            int nG, int nP, uint4* __restrict__ recG, uint4* __restrict__ recP,
                            unsigned int* __restrict__ keyAll, float* out) {
    const int idx = blockIdx.x * blockDim.x + threadIdx.x;
    if (idx == 0) out[0] = 0.0f;
    if (idx >= nG + nP) return;
    keyAll[idx] = 0u;
    const float* src;
    uint4* dst;
    if (idx < nG) { src = gts + 3 * (size_t)idx;          dst = recG + idx; }
    else          { src = preds + 3 * (size_t)(idx - nG); dst = recP + (idx - nG); }
    const float x = src[0], y = src[1], z = src[2];
    const float w = -0.5f * (x * x + y * y + z * z);
    const unsigned int xh = bf16hi(x), yh = bf16hi(y), zh = bf16hi(z), wh = bf16hi(w);
    const unsigned int xl = bf16hi(x - bf16f(xh));
    const unsigned int yl = bf16hi(y - bf16f(yh));
    const unsigned int zl = bf16hi(z - bf16f(zh));
    const unsigned int wl = bf16hi(w - bf16f(wh));
    *dst = make_uint4(xh | (yh << 16), zh | (wh << 16),
                      xl | (yl << 16), zl | (wl << 16));
}

__global__ void __launch_bounds__(BLOCK, 3)
nn_kernel(const uint4* __restrict__ recG, const uint4* __restrict__ recP,
          unsigned int* __restrict__ keyX, unsigned int* __restrict__ keyY,
          int N, int M, int B) {
    const int z = blockIdx.z;
    const bool dirX = (z < B);
    const int b = dirX ? z : z - B;
    const int NQ = dirX ? N : M;
    const int NR = dirX ? M : N;
    const uint4* Qr = (dirX ? recG : recP) + (size_t)b * NQ;
    const uint4* Rr = (dirX ? recP : recG) + (size_t)b * NR;
    unsigned int* keys = (dirX ? keyX : keyY) + (size_t)b * NQ;

    const int tid = threadIdx.x;
    const int lane = tid & 63;
    const int wave = tid >> 6;
    const int m = lane & 31;
    const bool hiK = lane >= 32;          // this half supplies k=8..15
    const int qBase = (blockIdx.x * WAVES + wave) * QPW;

    // ---- A fragments (two 32-row groups)
    const uint4 q0 = Qr[qBase + m];
    const uint4 q1 = Qr[qBase + 32 + m];
    U16S a;
    a.v.x = q0.x;                                   // (qxh, qyh)
    a.v.y = (q0.y & 0xFFFFu) | 0x3F800000u;         // (qzh, 1.0bf16)
    a.v.z = hiK ? 0u : q0.z;                        // (qxl, qyl) | 0
    a.v.w = hiK ? 0u : (q0.w & 0xFFFFu);            // (qzl, 0)   | 0
    const short8 A0 = a.s;
    a.v.x = q1.x;
    a.v.y = (q1.y & 0xFFFFu) | 0x3F800000u;
    a.v.z = hiK ? 0u : q1.z;
    a.v.w = hiK ? 0u : (q1.w & 0xFFFFu);
    const short8 A1 = a.s;

    f32x16 zc;
    #pragma unroll
    for (int r = 0; r < 16; ++r) zc[r] = 0.0f;
    f32x16 k0, k1;
    #pragma unroll
    for (int r = 0; r < 16; ++r) { k0[r] = -INFINITY; k1[r] = -INFINITY; }

    // B stream: record = 2 uint2; this lane reads half (hiK?1:0) of point m of
    // each 32-point tile. 64 lanes x 8B = 512B/tile, fully coalesced.
    const int chunk = NR / NCHUNK;
    const uint2* rp = (const uint2*)(Rr + (size_t)blockIdx.y * chunk) + 2 * m + (hiK ? 1 : 0);
    const int iters = chunk / 64;         // 2 tiles (64 refs) per iteration

    uint2 t0 = rp[0], t1 = rp[64];
    const uint2* p = rp;
    for (int it = 0; it < iters; ++it) {
        const uint2* pn = (it + 1 < iters) ? (p + 128) : rp;   // clamped prefetch
        const uint2 n0 = pn[0];
        const uint2 n1 = pn[64];

        U16S b0, b1;
        b0.v.x = t0.x; b0.v.y = t0.y;
        b0.v.z = hiK ? 0u : t0.x; b0.v.w = hiK ? 0u : t0.y;
        b1.v.x = t1.x; b1.v.y = t1.y;
        b1.v.z = hiK ? 0u : t1.x; b1.v.w = hiK ? 0u : t1.y;

        f32x16 c0 = mfma_bf16(A0, b0.s, zc);
        f32x16 c1 = mfma_bf16(A1, b0.s, zc);
        f32x16 c2 = mfma_bf16(A0, b1.s, zc);
        f32x16 c3 = mfma_bf16(A1, b1.s, zc);
        mfma_fence4(c0, c1, c2, c3);
        #pragma unroll
        for (int r = 0; r < 16; ++r) {
            k0[r] = fmaxf(fmaxf(c0[r], c2[r]), k0[r]);   // v_max3
            k1[r] = fmaxf(fmaxf(c1[r], c3[r]), k1[r]);
        }

        p = pn; t0 = n0; t1 = n1;
    }

    // ---- epilogue: max over 32 cols within each lane-half, then atomicMax
    // per row. C/D layout: col=lane&31, row=(r&3)+8*(r>>2)+4*(lane>>5).
    #pragma unroll
    for (int r = 0; r < 16; ++r) {
        float v0 = k0[r], v1 = k1[r];
        #pragma unroll
        for (int off = 16; off; off >>= 1) {
            v0 = fmaxf(v0, __shfl_xor(v0, off));
            v1 = fmaxf(v1, __shfl_xor(v1, off));
        }
        if (m == 0) {   // lanes 0 and 32
            const int row = (r & 3) + 8 * (r >> 2) + 4 * (lane >> 5);
            atomicMax(&keys[qBase + row], encodeKey(v0));
            atomicMax(&keys[qBase + 32 + row], encodeKey(v1));
        }
    }
}

// d2 = max(0, ||q||^2 - 2*Cmax); weighted means of both directions, one
// atomicAdd per block.
__global__ void __launch_bounds__(BLOCK)
reduce_kernel(const unsigned int* __restrict__ keyX, const float* __restrict__ gts, int nG,
              const unsigned int* __restrict__ keyY, const float* __restrict__ preds, int nP,
              float invx, float invy, float* __restrict__ out) {
    const int total = nG + nP;
    float local = 0.0f;
    for (int idx = blockIdx.x * blockDim.x + threadIdx.x; idx < total;
         idx += gridDim.x * blockDim.x) {
        if (idx < nG) {
            const float c = decodeKey(keyX[idx]);
            const float* q = gts + 3 * (size_t)idx;
            const float x2 = q[0] * q[0] + q[1] * q[1] + q[2] * q[2];
            local += fmaxf(x2 - 2.0f * c, 0.0f) * invx;
        } else {
            const int j = idx - nG;
            const float c = decodeKey(keyY[j]);
            const float* q = preds + 3 * (size_t)j;
            const float y2 = q[0] * q[0] + q[1] * q[1] + q[2] * q[2];
            local += fmaxf(y2 - 2.0f * c, 0.0f) * invy;
        }
    }
    __shared__ float waveSums[BLOCK / 64];
    float v = local;
    #pragma unroll
    for (int off = 32; off; off >>= 1) v += __shfl_xor(v, off);
    if ((threadIdx.x & 63) == 0) waveSums[threadIdx.x >> 6] = v;
    __syncthreads();
    if (threadIdx.x == 0) {
        float s = 0.0f;
        #pragma unroll
        for (int w = 0; w < BLOCK / 64; ++w) s += waveSums[w];
        atomicAdd(out, s);
    }
}

extern "C" void kernel_launch(void* const* d_in, const int* in_sizes, int n_in,
                              void* d_out, int out_size, void* d_ws, size_t ws_size,
                              hipStream_t stream) {
    const float* gts   = (const float*)d_in[0];   // [B, N, 3]
    const float* preds = (const float*)d_in[1];   // [B, M, 3]
    float* out = (float*)d_out;

    const int B = 8;
    const int N = in_sizes[0] / (B * 3);
    const int M = in_sizes[1] / (B * 3);
    const int nG = B * N, nP = B * M;

    uint4* recG = (uint4*)d_ws;                       // nG uint4
    uint4* recP = recG + nG;                          // nP uint4
    unsigned int* keyX = (unsigned int*)(recP + nP);  // nG uints
    unsigned int* keyY = keyX + nG;                   // nP uints

    prep_kernel<<<(nG + nP + BLOCK - 1) / BLOCK, BLOCK, 0, stream>>>(
        gts, preds, nG, nP, recG, recP, keyX, out);

    dim3 grid(N / (WAVES * QPW), NCHUNK, 2 * B);      // 32 x 4 x 16 = 2048 blocks
    nn_kernel<<<grid, BLOCK, 0, stream>>>(recG, recP, keyX, keyY, N, M, B);

    reduce_kernel<<<(nG + nP + BLOCK - 1) / BLOCK, BLOCK, 0, stream>>>(
        keyX, gts, nG, keyY, preds, nP, 1.0f / (float)nG, 1.0f / (float)nP, out);
}

// Round 6
// 98.757 us; speedup vs baseline: 1.1602x; 1.1602x over previous
//
#include <hip/hip_runtime.h>
#include <hip/hip_bf16.h>
#include <math.h>

// Chamfer distance via K-packed MFMA, B=8, N=M=8192, D=3, fp32.
//   C[m][n] = q_m.r_n - 0.5*||r_n||^2 via ONE v_mfma_f32_32x32x16_bf16:
//     lanes<32  (k0-7) : A={qh,1, ql,0}  B={rh,wh, rh,wh}
//     lanes>=32 (k8-15): A={qh,1, 0,0}   B={rl,wl, 0,0}
//   (hi/lo bf16 split; dropped ql.rl term ~2^-17 relative)
//   min_j d2 = ||q||^2_fp32 - 2*max_n C, clamped at 0.
// R6: NCHUNK=2 + 4-wave blocks -> 1024 blocks = exactly 4/CU resident;
// no atomics (per-chunk float stores, disjoint slots); LDS-transpose epilogue
// instead of 5-level shfl trees; distance-1 register prefetch, unroll 1.

#define BLOCK 256
#define WAVES 4
#define QPW 64        // queries per wave (two 32-row MFMA groups)
#define NCHUNK 2      // ref-dim split across blockIdx.y

typedef short short8 __attribute__((ext_vector_type(8)));
typedef float f32x16 __attribute__((ext_vector_type(16)));

union U16S { uint4 v; short8 s; };

__device__ __forceinline__ unsigned int bf16hi(float f) {
    __hip_bfloat16 h = __float2bfloat16(f);
    return (unsigned int)*reinterpret_cast<unsigned short*>(&h);
}
__device__ __forceinline__ float bf16f(unsigned int u) {
    unsigned short us = (unsigned short)u;
    __hip_bfloat16 h;
    *reinterpret_cast<unsigned short*>(&h) = us;
    return __bfloat162float(h);
}

__device__ __forceinline__ f32x16 mfma_bf16(short8 a, short8 b, f32x16 c) {
    f32x16 d;
    asm volatile("v_mfma_f32_32x32x16_bf16 %0, %1, %2, %3"
                 : "=v"(d) : "v"(a), "v"(b), "v"(c));
    return d;
}
// >=16 wait cycles between MFMA issue and VALU reads of dests (inline asm
// bypasses the compiler hazard recognizer); data-tied so folds can't hoist.
__device__ __forceinline__ void mfma_fence4(f32x16& a, f32x16& b, f32x16& c, f32x16& d) {
    asm volatile("s_nop 7\n\ts_nop 7" : "+v"(a), "+v"(b), "+v"(c), "+v"(d));
}

// Per point one 16B record: {xh|yh, zh|wh, xl|yl, zl|wl}, w = -0.5*||p||^2.
__global__ void prep_kernel(const float* __restrict__ gts, const float* __restrict__ preds,
                            int nG, int nP, uint4* __restrict__ recG, uint4* __restrict__ recP,
                            float* out) {
    const int idx = blockIdx.x * blockDim.x + threadIdx.x;
    if (idx == 0) out[0] = 0.0f;
    if (idx >= nG + nP) return;
    const float* src;
    uint4* dst;
    if (idx < nG) { src = gts + 3 * (size_t)idx;          dst = recG + idx; }
    else          { src = preds + 3 * (size_t)(idx - nG); dst = recP + (idx - nG); }
    const float x = src[0], y = src[1], z = src[2];
    const float w = -0.5f * (x * x + y * y + z * z);
    const unsigned int xh = bf16hi(x), yh = bf16hi(y), zh = bf16hi(z), wh = bf16hi(w);
    const unsigned int xl = bf16hi(x - bf16f(xh));
    const unsigned int yl = bf16hi(y - bf16f(yh));
    const unsigned int zl = bf16hi(z - bf16f(zh));
    const unsigned int wl = bf16hi(w - bf16f(wh));
    *dst = make_uint4(xh | (yh << 16), zh | (wh << 16),
                      xl | (yl << 16), zl | (wl << 16));
}

// kpart layout: float kpart[NCHUNK][nG + nP]; slot = blockIdx.y.
__global__ void __launch_bounds__(BLOCK, 4)
nn_kernel(const uint4* __restrict__ recG, const uint4* __restrict__ recP,
          float* __restrict__ kpart, int N, int M, int B) {
    const int z = blockIdx.z;
    const bool dirX = (z < B);
    const int b = dirX ? z : z - B;
    const int NQ = dirX ? N : M;
    const int NR = dirX ? M : N;
    const uint4* Qr = (dirX ? recG : recP) + (size_t)b * NQ;
    const uint4* Rr = (dirX ? recP : recG) + (size_t)b * NR;
    const int nGP = B * (N + M) / 2 * 2;   // == B*N + B*M
    float* outK = kpart + (size_t)blockIdx.y * nGP + (dirX ? 0 : B * N) + (size_t)b * NQ;

    const int tid = threadIdx.x;
    const int lane = tid & 63;
    const int wave = tid >> 6;
    const int m = lane & 31;
    const bool hiK = lane >= 32;                    // this half supplies k=8..15
    const unsigned int loMask = hiK ? 0u : 0xFFFFFFFFu;
    const int qBase = (blockIdx.x * WAVES + wave) * QPW;

    // ---- A fragments (two 32-row groups)
    const uint4 q0 = Qr[qBase + m];
    const uint4 q1 = Qr[qBase + 32 + m];
    U16S a;
    a.v.x = q0.x;                                   // (qxh, qyh)
    a.v.y = (q0.y & 0xFFFFu) | 0x3F800000u;         // (qzh, 1.0bf16)
    a.v.z = q0.z & loMask;                          // (qxl, qyl) | 0
    a.v.w = q0.w & 0xFFFFu & loMask;                // (qzl, 0)   | 0
    const short8 A0 = a.s;
    a.v.x = q1.x;
    a.v.y = (q1.y & 0xFFFFu) | 0x3F800000u;
    a.v.z = q1.z & loMask;
    a.v.w = q1.w & 0xFFFFu & loMask;
    const short8 A1 = a.s;

    f32x16 zc;
    #pragma unroll
    for (int r = 0; r < 16; ++r) zc[r] = 0.0f;
    f32x16 k0, k1;
    #pragma unroll
    for (int r = 0; r < 16; ++r) { k0[r] = -INFINITY; k1[r] = -INFINITY; }

    // B stream: record = 2 uint2; this lane reads half (hiK?1:0) of point m of
    // each 32-point tile. 64 lanes x 8B = 512B/tile, fully coalesced.
    const int chunk = NR / NCHUNK;
    const uint2* p = (const uint2*)(Rr + (size_t)blockIdx.y * chunk) + 2 * m + (hiK ? 1 : 0);
    const int iters = chunk / 64;                   // 64 refs (2 tiles) per iter

    uint2 t0 = p[0], t1 = p[64];
    #pragma unroll 1
    for (int it = 0; it < iters; ++it) {
        // distance-1 prefetch; last-iter overrun lands in the adjacent ws
        // region (rec*/kpart are contiguous) - loaded but never consumed.
        const uint2 n0 = p[128];
        const uint2 n1 = p[192];

        U16S b0, b1;
        b0.v.x = t0.x;          b0.v.y = t0.y;
        b0.v.z = t0.x & loMask; b0.v.w = t0.y & loMask;
        b1.v.x = t1.x;          b1.v.y = t1.y;
        b1.v.z = t1.x & loMask; b1.v.w = t1.y & loMask;

        f32x16 c0 = mfma_bf16(A0, b0.s, zc);
        f32x16 c1 = mfma_bf16(A1, b0.s, zc);
        f32x16 c2 = mfma_bf16(A0, b1.s, zc);
        f32x16 c3 = mfma_bf16(A1, b1.s, zc);
        mfma_fence4(c0, c1, c2, c3);
        #pragma unroll
        for (int r = 0; r < 16; ++r) {
            k0[r] = fmaxf(fmaxf(c0[r], c2[r]), k0[r]);   // v_max3
            k1[r] = fmaxf(fmaxf(c1[r], c3[r]), k1[r]);
        }

        t0 = n0; t1 = n1;
        p += 128;
    }

    // ---- epilogue: LDS transpose, then each lane max-reduces one query row.
    // C/D layout: col=lane&31, row=(r&3)+8*(r>>2)+4*(lane>>5).
    __shared__ float sT[WAVES][64][36];             // +4 pad: aligned, conflict-free
    #pragma unroll
    for (int r = 0; r < 16; ++r) {
        const int row = (r & 3) + 8 * (r >> 2) + 4 * (lane >> 5);
        sT[wave][row][m]      = k0[r];              // group 0 -> rows 0..31
        sT[wave][32 + row][m] = k1[r];              // group 1 -> rows 32..63
    }
    // wave-private region; compiler inserts the lgkmcnt waits.
    const float4* rowp = (const float4*)&sT[wave][lane][0];
    float4 m01 = rowp[0];
    #pragma unroll
    for (int kk = 1; kk < 8; ++kk) {
        const float4 t = rowp[kk];
        m01.x = fmaxf(m01.x, t.x); m01.y = fmaxf(m01.y, t.y);
        m01.z = fmaxf(m01.z, t.z); m01.w = fmaxf(m01.w, t.w);
    }
    const float cmax = fmaxf(fmaxf(m01.x, m01.y), fmaxf(m01.z, m01.w));
    outK[qBase + lane] = cmax;                      // coalesced, no atomics
}

// d2 = max(0, ||q||^2 - 2*max(kpart[0], kpart[1])); weighted means, one
// atomicAdd per block.
__global__ void __launch_bounds__(BLOCK)
reduce_kernel(const float* __restrict__ kpart, const float* __restrict__ gts, int nG,
              const float* __restrict__ preds, int nP,
              float invx, float invy, float* __restrict__ out) {
    const int total = nG + nP;
    float local = 0.0f;
    for (int idx = blockIdx.x * blockDim.x + threadIdx.x; idx < total;
         idx += gridDim.x * blockDim.x) {
        const float c = fmaxf(kpart[idx], kpart[total + idx]);
        const float* q;
        float inv;
        if (idx < nG) { q = gts + 3 * (size_t)idx;          inv = invx; }
        else          { q = preds + 3 * (size_t)(idx - nG); inv = invy; }
        const float q2 = q[0] * q[0] + q[1] * q[1] + q[2] * q[2];
        local += fmaxf(q2 - 2.0f * c, 0.0f) * inv;
    }
    __shared__ float waveSums[BLOCK / 64];
    float v = local;
    #pragma unroll
    for (int off = 32; off; off >>= 1) v += __shfl_xor(v, off);
    if ((threadIdx.x & 63) == 0) waveSums[threadIdx.x >> 6] = v;
    __syncthreads();
    if (threadIdx.x == 0) {
        float s = 0.0f;
        #pragma unroll
        for (int w = 0; w < BLOCK / 64; ++w) s += waveSums[w];
        atomicAdd(out, s);
    }
}

extern "C" void kernel_launch(void* const* d_in, const int* in_sizes, int n_in,
                              void* d_out, int out_size, void* d_ws, size_t ws_size,
                              hipStream_t stream) {
    const float* gts   = (const float*)d_in[0];   // [B, N, 3]
    const float* preds = (const float*)d_in[1];   // [B, M, 3]
    float* out = (float*)d_out;

    const int B = 8;
    const int N = in_sizes[0] / (B * 3);
    const int M = in_sizes[1] / (B * 3);
    const int nG = B * N, nP = B * M;

    uint4* recG  = (uint4*)d_ws;                  // nG uint4 (2 MB)
    uint4* recP  = recG + nG;                     // nP uint4 (2 MB)
    float* kpart = (float*)(recP + nP);           // NCHUNK * (nG+nP) floats (1 MB)

    prep_kernel<<<(nG + nP + BLOCK - 1) / BLOCK, BLOCK, 0, stream>>>(
        gts, preds, nG, nP, recG, recP, out);

    dim3 grid(N / (WAVES * QPW), NCHUNK, 2 * B);  // 32 x 2 x 16 = 1024 = 4/CU
    nn_kernel<<<grid, BLOCK, 0, stream>>>(recG, recP, kpart, N, M, B);

    reduce_kernel<<<256, BLOCK, 0, stream>>>(
        kpart, gts, nG, preds, nP, 1.0f / (float)nG, 1.0f / (float)nP, out);
}